// Round 1
// baseline (1254.508 us; speedup 1.0000x reference)
//
#include <hip/hip_runtime.h>
#include <math.h>

// Problem constants
#define N_   8
#define C_   32
#define CO_  32
#define K_   4
#define D_   24
#define H_   64
#define W_   64
#define HW_  (H_*W_)          // 4096
#define DHW_ (D_*HW_)         // 98304
#define WPC_ 27               // weights per (co,c): 3*3*3
#define WPN_ (CO_*C_*WPC_)    // 27648 combined weights per sample

// ---------------------------------------------------------------------------
// Kernel 1: per-(n,c) boundary-region sums for the attention-branch means.
// Each block handles (n, c, s) where s splits H into 4 chunks of 16 rows.
// Per thread: 45 accumulators = 5 sets {all-d, d==0, d==1, d==22, d==23} x
// 9 components {P, Rh0, Rh63, Cw0, Cw63, C00, C0_63, C63_0, C63_63}.
// ---------------------------------------------------------------------------
__global__ __launch_bounds__(256) void k_stats(const float* __restrict__ X,
                                               float* __restrict__ stats) {
    int blk = blockIdx.x;            // 1024 blocks
    int n = blk >> 7;                // /128
    int c = (blk >> 2) & 31;
    int s = blk & 3;
    const float* base = X + (size_t)(n * C_ + c) * DHW_ + s * 16 * W_;

    float acc[45];
#pragma unroll
    for (int j = 0; j < 45; j++) acc[j] = 0.f;

    int tid = threadIdx.x;
    // 24576 elements per block: d in [0,24), hl in [0,16), w in [0,64)
    for (int it = tid; it < 24576; it += 256) {
        int d  = it >> 10;           // 16*64 = 1024 elems per d-plane chunk
        int hl = (it >> 6) & 15;
        int w  = it & 63;
        int h  = s * 16 + hl;
        float v = base[d * HW_ + hl * W_ + w];

        float vh0  = (h == 0)  ? v : 0.f;
        float vh63 = (h == 63) ? v : 0.f;
        float vw0  = (w == 0)  ? v : 0.f;
        float vw63 = (w == 63) ? v : 0.f;
        float c00 = (h == 0  && w == 0)  ? v : 0.f;
        float c03 = (h == 0  && w == 63) ? v : 0.f;
        float c30 = (h == 63 && w == 0)  ? v : 0.f;
        float c33 = (h == 63 && w == 63) ? v : 0.f;

#define UPD(o) { acc[o]+=v; acc[o+1]+=vh0; acc[o+2]+=vh63; acc[o+3]+=vw0; \
                 acc[o+4]+=vw63; acc[o+5]+=c00; acc[o+6]+=c03; acc[o+7]+=c30; acc[o+8]+=c33; }
        UPD(0)                                    // set 0: all d
        // d is uniform per 256-thread iteration (256 | 1024) -> cheap branches
        if (d == 0)       UPD(9)
        else if (d == 1)  UPD(18)
        else if (d == 22) UPD(27)
        else if (d == 23) UPD(36)
#undef UPD
    }

    // wave reduce (64-wide) then cross-wave via LDS
    __shared__ float lds[4][45];
    int lane = tid & 63, wv = tid >> 6;
#pragma unroll
    for (int j = 0; j < 45; j++) {
        float v = acc[j];
#pragma unroll
        for (int off = 32; off > 0; off >>= 1) v += __shfl_down(v, off);
        if (lane == 0) lds[wv][j] = v;
    }
    __syncthreads();
    if (tid < 45) {
        float v = lds[0][tid] + lds[1][tid] + lds[2][tid] + lds[3][tid];
        stats[((size_t)(n * C_ + c) * 4 + s) * 45 + tid] = v;
    }
}

// ---------------------------------------------------------------------------
// Kernel 2: per-sample attention (box-sum means -> softmax) + combined
// weights  W_n[c][co][t] = conv_w[co][c][t] + sum_k att[n,k]*weight[k][co][c][t]
// Grid = N blocks of 256 threads.
// ---------------------------------------------------------------------------
__global__ __launch_bounds__(256) void k_att(const float* __restrict__ stats,
                                             const float* __restrict__ weight,
                                             const float* __restrict__ conv_w,
                                             const float* __restrict__ aw1,
                                             const float* __restrict__ ab1,
                                             const float* __restrict__ aw2,
                                             const float* __restrict__ ab2,
                                             const float* __restrict__ aw3,
                                             const float* __restrict__ ab3,
                                             float* __restrict__ wn_out) {
    int n = blockIdx.x;
    int tid = threadIdx.x;
    __shared__ float xaL[K_];
    __shared__ float attL[K_];

    if (tid < K_ * C_) {              // 128 active threads: (k, c)
        int k = tid >> 5;
        int c = tid & 31;
        const float* st = stats + (size_t)(n * C_ + c) * 4 * 45;
        float s45[45];
#pragma unroll
        for (int j = 0; j < 45; j++)
            s45[j] = st[j] + st[45 + j] + st[90 + j] + st[135 + j];

        // Qs[set][(oh+1)*3+(ow+1)] : plane-set sum restricted to (oh,ow) h/w range
        float Qs[5][9];
#pragma unroll
        for (int set = 0; set < 5; set++) {
            const float* S = s45 + set * 9;
#pragma unroll
            for (int oh = -1; oh <= 1; oh++) {
#pragma unroll
                for (int ow = -1; ow <= 1; ow++) {
                    float q = S[0];
                    if (oh == 1)  q -= S[1];
                    if (oh == -1) q -= S[2];
                    if (ow == 1)  q -= S[3];
                    if (ow == -1) q -= S[4];
                    if (oh == 1  && ow == 1)  q += S[5];
                    if (oh == 1  && ow == -1) q += S[6];
                    if (oh == -1 && ow == 1)  q += S[7];
                    if (oh == -1 && ow == -1) q += S[8];
                    Qs[set][(oh + 1) * 3 + (ow + 1)] = q;
                }
            }
        }
        // Box(od, qi): d-range excludes boundary planes per od
        auto box = [&](int od, int qi) {
            float b = Qs[0][qi];
            if (od == -2) b -= Qs[3][qi] + Qs[4][qi];
            if (od == -1) b -= Qs[4][qi];
            if (od ==  1) b -= Qs[1][qi];
            if (od ==  2) b -= Qs[1][qi] + Qs[2][qi];
            return b;
        };

        float sum = aw1[k * C_ + c] * Qs[0][4];   // 1x1x1 conv: full box
        const float* a2 = aw2 + (k * C_ + c) * 27;
        const float* a3 = aw3 + (k * C_ + c) * 45;
#pragma unroll
        for (int kd = 0; kd < 3; kd++)
#pragma unroll
            for (int kh = 0; kh < 3; kh++)
#pragma unroll
                for (int kw = 0; kw < 3; kw++)
                    sum += a2[kd * 9 + kh * 3 + kw] * box(kd - 1, kh * 3 + kw);
#pragma unroll
        for (int kd = 0; kd < 5; kd++)
#pragma unroll
            for (int kh = 0; kh < 3; kh++)
#pragma unroll
                for (int kw = 0; kw < 3; kw++)
                    sum += a3[kd * 9 + kh * 3 + kw] * box(kd - 2, kh * 3 + kw);

        // reduce over c (32 contiguous lanes)
#pragma unroll
        for (int off = 16; off > 0; off >>= 1) sum += __shfl_down(sum, off, 32);
        if ((tid & 31) == 0) xaL[k] = sum;
    }
    __syncthreads();
    if (tid == 0) {
        float xa[K_], mx = -1e30f;
#pragma unroll
        for (int k = 0; k < K_; k++) {
            xa[k] = xaL[k] * (1.f / (float)DHW_) + ab1[k] + ab2[k] + ab3[k];
            mx = fmaxf(mx, xa[k]);
        }
        float ssum = 0.f, e[K_];
#pragma unroll
        for (int k = 0; k < K_; k++) { e[k] = expf(xa[k] - mx); ssum += e[k]; }
#pragma unroll
        for (int k = 0; k < K_; k++) attL[k] = e[k] / ssum;
    }
    __syncthreads();

    float at0 = attL[0], at1 = attL[1], at2 = attL[2], at3 = attL[3];
    // combined weights, relaid out as [c][co][t] for contiguous scalar loads
    for (int i = tid; i < WPN_; i += 256) {
        int c  = i / (CO_ * WPC_);
        int r  = i - c * (CO_ * WPC_);
        int co = r / WPC_;
        int t  = r - co * WPC_;
        int src = (co * C_ + c) * WPC_ + t;     // (co,c,t) layout of inputs
        float v = conv_w[src] + at0 * weight[src] + at1 * weight[WPN_ + src]
                + at2 * weight[2 * WPN_ + src] + at3 * weight[3 * WPN_ + src];
        wn_out[(size_t)n * WPN_ + i] = v;
    }
}

// ---------------------------------------------------------------------------
// Kernel 3: main fused conv. Block = (n, d, h-block of 4). Thread = (h,w)
// position, accumulates all 32 co in registers. Weights via wave-uniform
// (scalar) loads -> inner loop is pure v_fmac_f32 with SGPR weight operand.
// ---------------------------------------------------------------------------
__global__ __launch_bounds__(256) void k_conv(const float* __restrict__ X,
                                              const float* __restrict__ Wn,
                                              const float* __restrict__ bias,
                                              float* __restrict__ out) {
    int blk = blockIdx.x;                 // 8*24*16 = 3072
    int n  = blk / (D_ * 16);
    int r  = blk - n * (D_ * 16);
    int d  = r >> 4;
    int hb = r & 15;
    int tid = threadIdx.x;
    int h = hb * 4 + (tid >> 6);          // uniform per wave
    int w = tid & 63;

    const float* wn = Wn + (size_t)n * WPN_;   // [c][co][t]
    float acc[CO_];
#pragma unroll
    for (int co = 0; co < CO_; co++) acc[co] = bias[co];

#pragma unroll 1
    for (int c = 0; c < C_; c++) {
        const float* xc = X + (size_t)(n * C_ + c) * DHW_;
        float xv[27];
#pragma unroll
        for (int od = 0; od < 3; od++) {
            int zd = d + od - 1;
            bool vd = (unsigned)zd < (unsigned)D_;
#pragma unroll
            for (int oh = 0; oh < 3; oh++) {
                int y = h + oh - 1;
                bool vy = (unsigned)y < (unsigned)H_;
#pragma unroll
                for (int ow = 0; ow < 3; ow++) {
                    int xx = w + ow - 1;
                    bool vx = (unsigned)xx < (unsigned)W_;
                    float val = 0.f;
                    if (vd && vy && vx) val = xc[(zd << 12) + (y << 6) + xx];
                    xv[od * 9 + oh * 3 + ow] = val;
                }
            }
        }
        const float* wc = wn + c * (CO_ * WPC_);
#pragma unroll
        for (int co = 0; co < CO_; co++) {
            float a = acc[co];
#pragma unroll
            for (int t = 0; t < WPC_; t++)
                a = fmaf(wc[co * WPC_ + t], xv[t], a);
            acc[co] = a;
        }
    }

    size_t sp = (size_t)d * HW_ + h * W_ + w;
#pragma unroll
    for (int co = 0; co < CO_; co++)
        out[(size_t)(n * CO_ + co) * DHW_ + sp] = acc[co];
}

extern "C" void kernel_launch(void* const* d_in, const int* in_sizes, int n_in,
                              void* d_out, int out_size, void* d_ws, size_t ws_size,
                              hipStream_t stream) {
    const float* x      = (const float*)d_in[0];
    const float* weight = (const float*)d_in[1];
    const float* conv_w = (const float*)d_in[2];
    const float* conv_b = (const float*)d_in[3];
    const float* aw1    = (const float*)d_in[4];
    const float* ab1    = (const float*)d_in[5];
    const float* aw2    = (const float*)d_in[6];
    const float* ab2    = (const float*)d_in[7];
    const float* aw3    = (const float*)d_in[8];
    const float* ab3    = (const float*)d_in[9];
    float* out = (float*)d_out;

    float* stats = (float*)d_ws;                    // N*C*4*45 = 46080 floats
    float* wn    = stats + (size_t)N_ * C_ * 4 * 45; // N*27648 floats

    k_stats<<<dim3(N_ * C_ * 4), dim3(256), 0, stream>>>(x, stats);
    k_att<<<dim3(N_), dim3(256), 0, stream>>>(stats, weight, conv_w,
                                              aw1, ab1, aw2, ab2, aw3, ab3, wn);
    k_conv<<<dim3(N_ * D_ * 16), dim3(256), 0, stream>>>(x, wn, conv_b, out);
}

// Round 2
// 461.398 us; speedup vs baseline: 2.7189x; 2.7189x over previous
//
#include <hip/hip_runtime.h>
#include <math.h>

// Problem constants
#define N_   8
#define C_   32
#define CO_  32
#define K_   4
#define D_   24
#define H_   64
#define W_   64
#define HW_  (H_*W_)          // 4096
#define DHW_ (D_*HW_)         // 98304
#define WPC_ 27               // taps per (co,c): 3*3*3
#define WPN_ (CO_*C_*WPC_)    // 27648 combined weights per sample

// padded transposed x: [n][dp=26][hp=66][wp=66][c=32] bf16 (halo = 0)
#define DP_ 26
#define HP_ 66
#define WP_ 66
#define XT_PER_N ((size_t)DP_*HP_*WP_*C_)       // 3,624,192 elems
#define XT_BYTES (XT_PER_N * N_ * 2)            // 57,987,072 B
#define STATS_BYTES ((size_t)N_*C_*4*45*4)      // 184,320 B

typedef float f32x4  __attribute__((ext_vector_type(4)));
typedef short bf16x8 __attribute__((ext_vector_type(8)));

__device__ inline unsigned short f2bf(float f) {
    unsigned u = __float_as_uint(f);
    unsigned r = (u + 0x7fffu + ((u >> 16) & 1u)) >> 16;
    return (unsigned short)r;
}

// ---------------------------------------------------------------------------
// Kernel 0: pack x (fp32 NCDHW) -> x_t (bf16, [n][dp][hp][wp][c], zero halo).
// Block = one padded row (n, dp, hp): 66 wp x 32 c. Writes fully coalesced.
// ---------------------------------------------------------------------------
__global__ __launch_bounds__(256) void k_pack(const float* __restrict__ X,
                                              unsigned short* __restrict__ xt) {
    int blk = blockIdx.x;                 // n*DP_*HP_ + dp*HP_ + hp
    int hp  = blk % HP_;
    int t2  = blk / HP_;
    int dp  = t2 % DP_;
    int n   = t2 / DP_;
    int d = dp - 1, h = hp - 1;
    int tid = threadIdx.x;
    int c  = tid & 31;
    int wg = tid >> 5;                    // 0..7
    unsigned short* orow = xt + (size_t)blk * (WP_ * C_);
    bool vdh = ((unsigned)d < (unsigned)D_) && ((unsigned)h < (unsigned)H_);
    const float* xrow = X + ((size_t)(n * C_ + c)) * DHW_
                          + (size_t)(d < 0 ? 0 : d) * HW_
                          + (size_t)(h < 0 ? 0 : h) * W_;
#pragma unroll
    for (int g = 0; g < 9; g++) {
        int wp = wg + (g << 3);           // covers 0..71
        if (wp < WP_) {
            int w = wp - 1;
            float v = 0.f;
            if (vdh && (unsigned)w < (unsigned)W_) v = xrow[w];
            orow[wp * C_ + c] = f2bf(v);
        }
    }
}

// ---------------------------------------------------------------------------
// Kernel 1: per-(n,c) boundary-region sums for the attention-branch means.
// (unchanged from R1 — verified correct)
// ---------------------------------------------------------------------------
__global__ __launch_bounds__(256) void k_stats(const float* __restrict__ X,
                                               float* __restrict__ stats) {
    int blk = blockIdx.x;            // 1024 blocks
    int n = blk >> 7;
    int c = (blk >> 2) & 31;
    int s = blk & 3;
    const float* base = X + (size_t)(n * C_ + c) * DHW_ + s * 16 * W_;

    float acc[45];
#pragma unroll
    for (int j = 0; j < 45; j++) acc[j] = 0.f;

    int tid = threadIdx.x;
    for (int it = tid; it < 24576; it += 256) {
        int d  = it >> 10;
        int hl = (it >> 6) & 15;
        int w  = it & 63;
        int h  = s * 16 + hl;
        float v = base[d * HW_ + hl * W_ + w];

        float vh0  = (h == 0)  ? v : 0.f;
        float vh63 = (h == 63) ? v : 0.f;
        float vw0  = (w == 0)  ? v : 0.f;
        float vw63 = (w == 63) ? v : 0.f;
        float c00 = (h == 0  && w == 0)  ? v : 0.f;
        float c03 = (h == 0  && w == 63) ? v : 0.f;
        float c30 = (h == 63 && w == 0)  ? v : 0.f;
        float c33 = (h == 63 && w == 63) ? v : 0.f;

#define UPD(o) { acc[o]+=v; acc[o+1]+=vh0; acc[o+2]+=vh63; acc[o+3]+=vw0; \
                 acc[o+4]+=vw63; acc[o+5]+=c00; acc[o+6]+=c03; acc[o+7]+=c30; acc[o+8]+=c33; }
        UPD(0)
        if (d == 0)       UPD(9)
        else if (d == 1)  UPD(18)
        else if (d == 22) UPD(27)
        else if (d == 23) UPD(36)
#undef UPD
    }

    __shared__ float lds[4][45];
    int lane = tid & 63, wv = tid >> 6;
#pragma unroll
    for (int j = 0; j < 45; j++) {
        float v = acc[j];
#pragma unroll
        for (int off = 32; off > 0; off >>= 1) v += __shfl_down(v, off);
        if (lane == 0) lds[wv][j] = v;
    }
    __syncthreads();
    if (tid < 45) {
        float v = lds[0][tid] + lds[1][tid] + lds[2][tid] + lds[3][tid];
        stats[((size_t)(n * C_ + c) * 4 + s) * 45 + tid] = v;
    }
}

// ---------------------------------------------------------------------------
// Kernel 2: attention softmax + combined weights -> bf16 in MFMA-A layout
// wn[n][t][co][c]  (c contiguous => one dwordx4 per lane A-fragment)
// ---------------------------------------------------------------------------
__global__ __launch_bounds__(256) void k_att(const float* __restrict__ stats,
                                             const float* __restrict__ weight,
                                             const float* __restrict__ conv_w,
                                             const float* __restrict__ aw1,
                                             const float* __restrict__ ab1,
                                             const float* __restrict__ aw2,
                                             const float* __restrict__ ab2,
                                             const float* __restrict__ aw3,
                                             const float* __restrict__ ab3,
                                             unsigned short* __restrict__ wn_out) {
    int n = blockIdx.x;
    int tid = threadIdx.x;
    __shared__ float xaL[K_];
    __shared__ float attL[K_];

    if (tid < K_ * C_) {
        int k = tid >> 5;
        int c = tid & 31;
        const float* st = stats + (size_t)(n * C_ + c) * 4 * 45;
        float s45[45];
#pragma unroll
        for (int j = 0; j < 45; j++)
            s45[j] = st[j] + st[45 + j] + st[90 + j] + st[135 + j];

        float Qs[5][9];
#pragma unroll
        for (int set = 0; set < 5; set++) {
            const float* S = s45 + set * 9;
#pragma unroll
            for (int oh = -1; oh <= 1; oh++) {
#pragma unroll
                for (int ow = -1; ow <= 1; ow++) {
                    float q = S[0];
                    if (oh == 1)  q -= S[1];
                    if (oh == -1) q -= S[2];
                    if (ow == 1)  q -= S[3];
                    if (ow == -1) q -= S[4];
                    if (oh == 1  && ow == 1)  q += S[5];
                    if (oh == 1  && ow == -1) q += S[6];
                    if (oh == -1 && ow == 1)  q += S[7];
                    if (oh == -1 && ow == -1) q += S[8];
                    Qs[set][(oh + 1) * 3 + (ow + 1)] = q;
                }
            }
        }
        auto box = [&](int od, int qi) {
            float b = Qs[0][qi];
            if (od == -2) b -= Qs[3][qi] + Qs[4][qi];
            if (od == -1) b -= Qs[4][qi];
            if (od ==  1) b -= Qs[1][qi];
            if (od ==  2) b -= Qs[1][qi] + Qs[2][qi];
            return b;
        };

        float sum = aw1[k * C_ + c] * Qs[0][4];
        const float* a2 = aw2 + (k * C_ + c) * 27;
        const float* a3 = aw3 + (k * C_ + c) * 45;
#pragma unroll
        for (int kd = 0; kd < 3; kd++)
#pragma unroll
            for (int kh = 0; kh < 3; kh++)
#pragma unroll
                for (int kw = 0; kw < 3; kw++)
                    sum += a2[kd * 9 + kh * 3 + kw] * box(kd - 1, kh * 3 + kw);
#pragma unroll
        for (int kd = 0; kd < 5; kd++)
#pragma unroll
            for (int kh = 0; kh < 3; kh++)
#pragma unroll
                for (int kw = 0; kw < 3; kw++)
                    sum += a3[kd * 9 + kh * 3 + kw] * box(kd - 2, kh * 3 + kw);

#pragma unroll
        for (int off = 16; off > 0; off >>= 1) sum += __shfl_down(sum, off, 32);
        if ((tid & 31) == 0) xaL[k] = sum;
    }
    __syncthreads();
    if (tid == 0) {
        float xa[K_], mx = -1e30f;
#pragma unroll
        for (int k = 0; k < K_; k++) {
            xa[k] = xaL[k] * (1.f / (float)DHW_) + ab1[k] + ab2[k] + ab3[k];
            mx = fmaxf(mx, xa[k]);
        }
        float ssum = 0.f, e[K_];
#pragma unroll
        for (int k = 0; k < K_; k++) { e[k] = expf(xa[k] - mx); ssum += e[k]; }
#pragma unroll
        for (int k = 0; k < K_; k++) attL[k] = e[k] / ssum;
    }
    __syncthreads();

    float at0 = attL[0], at1 = attL[1], at2 = attL[2], at3 = attL[3];
    for (int i = tid; i < WPN_; i += 256) {
        int t  = i >> 10;               // tap
        int rr = i & 1023;
        int co = rr >> 5;
        int c  = rr & 31;
        int src = (co * C_ + c) * WPC_ + t;
        float v = conv_w[src] + at0 * weight[src] + at1 * weight[WPN_ + src]
                + at2 * weight[2 * WPN_ + src] + at3 * weight[3 * WPN_ + src];
        wn_out[(size_t)n * WPN_ + i] = f2bf(v);
    }
}

// ---------------------------------------------------------------------------
// Kernel 3: implicit-GEMM conv via mfma_f32_16x16x32_bf16.
// K = 32 channels per mfma (one tap per K-step; 27 steps).
// Block = (n, d, h-block of 8); 4 waves, each: 2 rows x 4 w-tiles x 32 co.
// B frag = single dwordx4 from padded x_t (no masking). A frag from wn.
// ---------------------------------------------------------------------------
__global__ __launch_bounds__(256) void k_conv(const unsigned short* __restrict__ xt,
                                              const unsigned short* __restrict__ wn,
                                              const float* __restrict__ bias,
                                              float* __restrict__ out) {
    int blk = blockIdx.x;                 // n*D_*8 + d*8 + hb
    int hb = blk & 7;
    int t2 = blk >> 3;
    int d  = t2 % D_;
    int n  = t2 / D_;
    int h0 = hb << 3;

    int tid = threadIdx.x;
    int l   = tid & 63;
    int wid = tid >> 6;
    int nl  = l & 15;                     // spatial-in-tile (B n-dim, A m-dim)
    int kc  = (l >> 4) << 3;              // k-group base (c)

    const unsigned short* wa = wn + (size_t)n * WPN_;
    const unsigned short* ap_base = wa + nl * C_ + kc;     // + t*1024 per tap

    // per-(row,tile) lane offsets into a padded row-plane
    int voff[2][4];
#pragma unroll
    for (int r = 0; r < 2; r++)
#pragma unroll
        for (int wq = 0; wq < 4; wq++)
            voff[r][wq] = ((wid * 2 + r) * WP_ + wq * 16 + nl) * C_ + kc;

    f32x4 acc[2][4][2];
#pragma unroll
    for (int r = 0; r < 2; r++)
#pragma unroll
        for (int wq = 0; wq < 4; wq++)
#pragma unroll
            for (int hf = 0; hf < 2; hf++)
                acc[r][wq][hf] = (f32x4){0.f, 0.f, 0.f, 0.f};

#pragma unroll 1
    for (int od = 0; od < 3; od++) {
#pragma unroll
        for (int oh = 0; oh < 3; oh++) {
            const unsigned short* rowb =
                xt + ((size_t)(n * DP_ + d + od) * HP_ + (h0 + oh)) * (WP_ * C_);
#pragma unroll
            for (int ow = 0; ow < 3; ow++) {
                int t = (od * 3 + oh) * 3 + ow;
                const unsigned short* ap = ap_base + t * (CO_ * C_);
                bf16x8 A0 = *(const bf16x8*)(ap);
                bf16x8 A1 = *(const bf16x8*)(ap + 16 * C_);
#pragma unroll
                for (int r = 0; r < 2; r++)
#pragma unroll
                    for (int wq = 0; wq < 4; wq++) {
                        bf16x8 B = *(const bf16x8*)(rowb + voff[r][wq] + ow * C_);
                        acc[r][wq][0] = __builtin_amdgcn_mfma_f32_16x16x32_bf16(
                            A0, B, acc[r][wq][0], 0, 0, 0);
                        acc[r][wq][1] = __builtin_amdgcn_mfma_f32_16x16x32_bf16(
                            A1, B, acc[r][wq][1], 0, 0, 0);
                    }
            }
        }
    }

    // epilogue: D layout col=l&15 (spatial), row=(l>>4)*4+reg (co within half)
    int rquad = (l >> 4) << 2;
#pragma unroll
    for (int hf = 0; hf < 2; hf++)
#pragma unroll
        for (int j = 0; j < 4; j++) {
            int co = hf * 16 + rquad + j;
            float bv = bias[co];
#pragma unroll
            for (int r = 0; r < 2; r++) {
                int h = h0 + wid * 2 + r;
                float* op = out + ((size_t)(n * CO_ + co)) * DHW_
                                + (size_t)d * HW_ + (size_t)h * W_;
#pragma unroll
                for (int wq = 0; wq < 4; wq++)
                    op[wq * 16 + nl] = acc[r][wq][hf][j] + bv;
            }
        }
}

extern "C" void kernel_launch(void* const* d_in, const int* in_sizes, int n_in,
                              void* d_out, int out_size, void* d_ws, size_t ws_size,
                              hipStream_t stream) {
    const float* x      = (const float*)d_in[0];
    const float* weight = (const float*)d_in[1];
    const float* conv_w = (const float*)d_in[2];
    const float* conv_b = (const float*)d_in[3];
    const float* aw1    = (const float*)d_in[4];
    const float* ab1    = (const float*)d_in[5];
    const float* aw2    = (const float*)d_in[6];
    const float* ab2    = (const float*)d_in[7];
    const float* aw3    = (const float*)d_in[8];
    const float* ab3    = (const float*)d_in[9];
    float* out = (float*)d_out;

    unsigned short* xt  = (unsigned short*)d_ws;
    float* stats        = (float*)((char*)d_ws + XT_BYTES);
    unsigned short* wnb = (unsigned short*)((char*)d_ws + XT_BYTES + STATS_BYTES);

    k_pack<<<dim3(N_ * DP_ * HP_), dim3(256), 0, stream>>>(x, xt);
    k_stats<<<dim3(N_ * C_ * 4), dim3(256), 0, stream>>>(x, stats);
    k_att<<<dim3(N_), dim3(256), 0, stream>>>(stats, weight, conv_w,
                                              aw1, ab1, aw2, ab2, aw3, ab3, wnb);
    k_conv<<<dim3(N_ * D_ * 8), dim3(256), 0, stream>>>(xt, wnb, conv_b, out);
}